// Round 2
// baseline (457.172 us; speedup 1.0000x reference)
//
#include <hip/hip_runtime.h>
#include <cstdint>
#include <cstddef>

#define NN 207      // nodes
#define NE 1722     // edges
#define NT 24       // time buckets
#define LL 2048     // L
#define LCC 128     // columns per block (8 waves x 16 cols)
#define KP  208     // padded K rows in LDS (13*16); K-tile 7 hi-half is register zeros
#define MTILES 13   // 13*16 = 208 >= 207
#define KTILES 7    // 7 x K32 MFMA per (mt, mat); tile 6 hi-half zero
#define CH_U16 3584 // u16 per (t,mt,mat) chunk: 7*512
#define T_U16 (MTILES * 3 * CH_U16)   // 139776 u16 per t

// ws layout (bytes):
// cb4   @ 0       : float4[NT*NN] {c_r, c_ra, c_d+c_da, 0}        (79488 B)
// bb4   @ 79488   : float4[NT*NN] {b_r, b_ra, b_d+b_da, 0}        (79488 B)
// Wpack @ 158976  : f16 MFMA-A-fragment-packed dense weights, 24*139776*2 = 6709248 B

typedef float    f32x4 __attribute__((ext_vector_type(4)));
typedef _Float16 half8 __attribute__((ext_vector_type(8)));

__device__ __forceinline__ unsigned short f2h(float f) {
    return __builtin_bit_cast(unsigned short, (_Float16)f);
}
__device__ __forceinline__ float tanhfast(float z) {
    return 1.0f - __fdividef(2.0f, __expf(2.0f * z) + 1.0f);
}

// K1: per (t, 16-row tile): build dense rows of the 3 matrices in LDS (f32),
// diag/colsum + bias tables, emit f16 fragments pre-packed in MFMA A order.
// W_R = -Ar, W_RA = +Ara, W_D = Ada - Ad  (diagonals applied in f32 epilogue of K2).
__global__ void k_build(const int* __restrict__ efrom, const int* __restrict__ eto,
                        const float* __restrict__ wr, const float* __restrict__ wd,
                        const float* __restrict__ wra, const float* __restrict__ wda,
                        const float* __restrict__ br, const float* __restrict__ bd,
                        const float* __restrict__ bra, const float* __restrict__ bda,
                        unsigned short* __restrict__ Wpack,
                        float4* __restrict__ cb4, float4* __restrict__ bb4) {
    const int t   = blockIdx.x / MTILES;
    const int mt  = blockIdx.x % MTILES;
    const int tid = threadIdx.x;              // 256
    __shared__ float rowbuf[3][16][KP];       // 39936 B
    __shared__ float cs[4][16];

    float* rb = &rowbuf[0][0][0];
    for (int i = tid; i < 3 * 16 * KP; i += 256) rb[i] = 0.0f;
    if (tid < 64) ((float*)cs)[tid] = 0.0f;
    __syncthreads();

    const int mt16 = mt * 16;
    const float* wrt  = wr  + (size_t)t * NE;
    const float* wdt  = wd  + (size_t)t * NE;
    const float* wrat = wra + (size_t)t * NE;
    const float* wdat = wda + (size_t)t * NE;
    for (int e = tid; e < NE; e += 256) {
        int ef = efrom[e], et = eto[e];
        unsigned rf = (unsigned)(ef - mt16), rt = (unsigned)(et - mt16);
        bool in_f = rf < 16u, in_t = rt < 16u;
        if (in_f || in_t) {
            float w1 = wrt[e], w2 = wdt[e], w3 = wrat[e], w4 = wdat[e];
            if (in_t) {                       // Ad/Ada live at [to][from]; Ar/Ara colsums
                atomicAdd(&rowbuf[2][rt][ef], w4 - w2);
                atomicAdd(&cs[0][rt], w1);
                atomicAdd(&cs[1][rt], w3);
            }
            if (in_f) {                       // Ar/Ara live at [from][to]; Ad/Ada colsums
                atomicAdd(&rowbuf[0][rf][et], -w1);
                atomicAdd(&rowbuf[1][rf][et],  w3);
                atomicAdd(&cs[2][rf], w2);
                atomicAdd(&cs[3][rf], w4);
            }
        }
    }
    __syncthreads();

    if (tid < 16) {
        int w = mt16 + tid;
        if (w < NN) {
            cb4[t * NN + w] = make_float4(cs[0][tid], cs[1][tid], cs[2][tid] + cs[3][tid], 0.0f);
            bb4[t * NN + w] = make_float4(br[t * NN + w], bra[t * NN + w],
                                          bd[t * NN + w] + bda[t * NN + w], 0.0f);
        }
    }

    // pack A-fragments: lane l=(g,r): elems 0..3 = W[r][ks*32+4g+e], 4..7 = +16 (0 if >=KP)
    for (int fr = tid; fr < 3 * KTILES * 64; fr += 256) {
        int mat = fr / (KTILES * 64);
        int rem = fr - mat * (KTILES * 64);
        int ks = rem >> 6, lq = rem & 63;
        int r = lq & 15, g = lq >> 4;
        const float* src = &rowbuf[mat][r][0];
        int k0 = ks * 32 + 4 * g;
        unsigned short h[8];
        #pragma unroll
        for (int e2 = 0; e2 < 4; ++e2) {
            h[e2] = f2h(src[k0 + e2]);                              // k0+e2 <= 207 always
            int kb = k0 + 16 + e2;
            h[4 + e2] = (kb < KP) ? f2h(src[kb]) : (unsigned short)0;
        }
        uint4 pv;
        pv.x = (unsigned)h[0] | ((unsigned)h[1] << 16);
        pv.y = (unsigned)h[2] | ((unsigned)h[3] << 16);
        pv.z = (unsigned)h[4] | ((unsigned)h[5] << 16);
        pv.w = (unsigned)h[6] | ((unsigned)h[7] << 16);
        size_t o = ((size_t)(t * MTILES + mt) * 3 + mat) * CH_U16 + (size_t)ks * 512 + (size_t)lq * 8;
        *(uint4*)(Wpack + o) = pv;
    }
}

// K2: MFMA main. Block (chunk, b): 512 thr = 8 waves, wave wv owns 16 cols.
// x staged row-major f16 [KP][LCC] with XOR swizzle col^=((k>>2)&3)<<3 (2-way max on
// every access phase). 53,248 B LDS -> 3 blocks/CU. B-frags register-resident; A streamed
// linearly from packed global; epilogue xq from LDS f16, cb/bb tables direct (L1-hot).
__global__ __launch_bounds__(512, 6) void k_mfma(
    const float* __restrict__ inputs, const int* __restrict__ ind,
    const unsigned short* __restrict__ Wpack,
    const float4* __restrict__ cb4, const float4* __restrict__ bb4,
    float* __restrict__ out) {
    __shared__ unsigned short xs[KP * LCC];   // 53248 B
    const int b = blockIdx.y, chunk = blockIdx.x, tid = threadIdx.x;
    const int t = ind[b] / 12;

    // zero pad row 207 (read by frag build for g=3,e=3 and guarded out of epilogue)
    if (tid < 64) ((unsigned*)(xs + 207 * LCC))[tid] = 0u;

    // stage x rows 0..206, swizzled
    const float* xb = inputs + (size_t)b * (2 * NN * LL) + (size_t)chunk * LCC;
    for (int i = tid; i < 207 * 32; i += 512) {
        int k  = i >> 5;
        int c4 = (i & 31) << 2;
        float4 v = *(const float4*)(xb + (size_t)k * LL + c4);
        int gk = (k >> 2) & 3;
        ushort4 h;
        h.x = f2h(v.x); h.y = f2h(v.y); h.z = f2h(v.z); h.w = f2h(v.w);
        *(ushort4*)&xs[k * LCC + (c4 ^ (gk << 3))] = h;
    }
    __syncthreads();

    const int l  = tid & 63, wv = tid >> 6;
    const int r  = l & 15,  g  = l >> 4;
    const int col  = wv * 16 + r;
    const int colx = col ^ (g << 3);           // swizzled col: (k>>2)&3 == g for all our reads
    const _Float16* xh = (const _Float16*)xs;

    // B fragments: B[k][col]; elems 0..3 = k in [4g,4g+3], 4..7 = +16; tile 6 hi = 0
    half8 bf[KTILES];
    #pragma unroll
    for (int ks = 0; ks < KTILES - 1; ++ks) {
        half8 v;
        int k0 = ks * 32 + 4 * g;
        #pragma unroll
        for (int e = 0; e < 4; ++e) {
            v[e]     = xh[(k0 + e) * LCC + colx];
            v[4 + e] = xh[(k0 + 16 + e) * LCC + colx];
        }
        bf[ks] = v;
    }
    {
        half8 v = {0, 0, 0, 0, 0, 0, 0, 0};
        int k0 = 192 + 4 * g;
        #pragma unroll
        for (int e = 0; e < 4; ++e) v[e] = xh[(k0 + e) * LCC + colx];   // row 207 is zero
        bf[KTILES - 1] = v;
    }

    const unsigned short* Ap = Wpack + (size_t)t * T_U16 + (size_t)l * 8;
    const float4* cbp = cb4 + (size_t)t * NN;
    const float4* bbp = bb4 + (size_t)t * NN;
    float* ob = out + (size_t)b * ((size_t)NN * LL) + (size_t)chunk * LCC + col;

    for (int mt = 0; mt < MTILES; ++mt) {
        f32x4 aR = {0.f, 0.f, 0.f, 0.f};
        f32x4 aA = {0.f, 0.f, 0.f, 0.f};
        f32x4 aD = {0.f, 0.f, 0.f, 0.f};
        #pragma unroll
        for (int ks = 0; ks < KTILES; ++ks) {
            half8 a = __builtin_bit_cast(half8, *(const uint4*)(Ap + ks * 512));
            aR = __builtin_amdgcn_mfma_f32_16x16x32_f16(a, bf[ks], aR, 0, 0, 0);
        }
        #pragma unroll
        for (int ks = 0; ks < KTILES; ++ks) {
            half8 a = __builtin_bit_cast(half8, *(const uint4*)(Ap + CH_U16 + ks * 512));
            aA = __builtin_amdgcn_mfma_f32_16x16x32_f16(a, bf[ks], aA, 0, 0, 0);
        }
        #pragma unroll
        for (int ks = 0; ks < KTILES; ++ks) {
            half8 a = __builtin_bit_cast(half8, *(const uint4*)(Ap + 2 * CH_U16 + ks * 512));
            aD = __builtin_amdgcn_mfma_f32_16x16x32_f16(a, bf[ks], aD, 0, 0, 0);
        }
        Ap += 3 * CH_U16;

        const int rowb = mt * 16 + 4 * g;      // C/D row = 4g+q, col = lane&15
        #pragma unroll
        for (int q = 0; q < 4; ++q) {
            int row = rowb + q;
            if (row < NN) {
                float xq = (float)xh[row * LCC + colx];
                float4 cb = cbp[row], bb = bbp[row];
                float rr = aR[q] + cb.x * xq + bb.x;
                float ra = aA[q] + bb.y;
                if (b != 0) ra += cb.y * xq;   // colsum(RW[0]) == 0 analytically
                float dd = aD[q] + cb.z * xq + bb.z;
                ob[(size_t)row * LL] = tanhfast(rr) + tanhfast(ra) + dd + xq;
            }
        }
    }
}

extern "C" void kernel_launch(void* const* d_in, const int* in_sizes, int n_in,
                              void* d_out, int out_size, void* d_ws, size_t ws_size,
                              hipStream_t stream) {
    const float* inputs = (const float*)d_in[0];
    const int*   ind    = (const int*)d_in[1];
    const int*   efrom  = (const int*)d_in[2];
    const int*   eto    = (const int*)d_in[3];
    const float* wr     = (const float*)d_in[4];
    const float* wd     = (const float*)d_in[5];
    const float* wra    = (const float*)d_in[6];
    const float* wda    = (const float*)d_in[7];
    const float* br     = (const float*)d_in[8];
    const float* bd     = (const float*)d_in[9];
    const float* bra    = (const float*)d_in[10];
    const float* bda    = (const float*)d_in[11];
    float* out = (float*)d_out;

    char* ws = (char*)d_ws;
    float4*         cb4   = (float4*)(ws + 0);
    float4*         bb4   = (float4*)(ws + 79488);
    unsigned short* Wpack = (unsigned short*)(ws + 158976);

    const int B = in_sizes[1];   // 64

    k_build<<<dim3(NT * MTILES), dim3(256), 0, stream>>>(
        efrom, eto, wr, wd, wra, wda, br, bd, bra, bda, Wpack, cb4, bb4);
    k_mfma<<<dim3(LL / LCC, B), dim3(512), 0, stream>>>(
        inputs, ind, Wpack, cb4, bb4, out);
}

// Round 4
// 421.557 us; speedup vs baseline: 1.0845x; 1.0845x over previous
//
#include <hip/hip_runtime.h>
#include <cstdint>
#include <cstddef>

#define NN 207      // nodes
#define NE 1722     // edges
#define NT 24       // time buckets
#define LL 2048     // L
#define LCC 128     // columns per block (8 waves x 16 cols)
#define KP  208     // padded K rows in LDS (13*16); K-tile 7 hi-half is register zeros
#define MTILES 13   // 13*16 = 208 >= 207
#define KTILES 7    // 7 x K32 MFMA per (mt, mat); tile 6 hi-half zero
#define CH_U16 3584 // u16 per (t,mt,mat) chunk: 7*512
#define T_U16 (MTILES * 3 * CH_U16)   // 139776 u16 per t

// ws layout (bytes):
// cb4   @ 0       : float4[NT*NN] {c_r, c_ra, c_d+c_da, 0}        (79488 B)
// bb4   @ 79488   : float4[NT*NN] {b_r, b_ra, b_d+b_da, 0}        (79488 B)
// Wpack @ 158976  : f16 MFMA-A-fragment-packed dense weights, 24*139776*2 = 6709248 B

typedef float    f32x4 __attribute__((ext_vector_type(4)));
typedef _Float16 half8 __attribute__((ext_vector_type(8)));

__device__ __forceinline__ unsigned short f2h(float f) {
    return __builtin_bit_cast(unsigned short, (_Float16)f);
}
__device__ __forceinline__ float tanhfast(float z) {
    return 1.0f - __fdividef(2.0f, __expf(2.0f * z) + 1.0f);
}

// K1: per (t, 16-row tile): build dense rows of the 3 matrices in LDS (f32),
// diag/colsum + bias tables, emit f16 fragments pre-packed in MFMA A order.
// W_R = -Ar, W_RA = +Ara, W_D = Ada - Ad  (diagonals applied in f32 epilogue of K2).
__global__ void k_build(const int* __restrict__ efrom, const int* __restrict__ eto,
                        const float* __restrict__ wr, const float* __restrict__ wd,
                        const float* __restrict__ wra, const float* __restrict__ wda,
                        const float* __restrict__ br, const float* __restrict__ bd,
                        const float* __restrict__ bra, const float* __restrict__ bda,
                        unsigned short* __restrict__ Wpack,
                        float4* __restrict__ cb4, float4* __restrict__ bb4) {
    const int t   = blockIdx.x / MTILES;
    const int mt  = blockIdx.x % MTILES;
    const int tid = threadIdx.x;              // 256
    __shared__ float rowbuf[3][16][KP];       // 39936 B
    __shared__ float cs[4][16];

    float* rb = &rowbuf[0][0][0];
    for (int i = tid; i < 3 * 16 * KP; i += 256) rb[i] = 0.0f;
    if (tid < 64) ((float*)cs)[tid] = 0.0f;
    __syncthreads();

    const int mt16 = mt * 16;
    const float* wrt  = wr  + (size_t)t * NE;
    const float* wdt  = wd  + (size_t)t * NE;
    const float* wrat = wra + (size_t)t * NE;
    const float* wdat = wda + (size_t)t * NE;
    for (int e = tid; e < NE; e += 256) {
        int ef = efrom[e], et = eto[e];
        unsigned rf = (unsigned)(ef - mt16), rt = (unsigned)(et - mt16);
        bool in_f = rf < 16u, in_t = rt < 16u;
        if (in_f || in_t) {
            float w1 = wrt[e], w2 = wdt[e], w3 = wrat[e], w4 = wdat[e];
            if (in_t) {                       // Ad/Ada live at [to][from]; Ar/Ara colsums
                atomicAdd(&rowbuf[2][rt][ef], w4 - w2);
                atomicAdd(&cs[0][rt], w1);
                atomicAdd(&cs[1][rt], w3);
            }
            if (in_f) {                       // Ar/Ara live at [from][to]; Ad/Ada colsums
                atomicAdd(&rowbuf[0][rf][et], -w1);
                atomicAdd(&rowbuf[1][rf][et],  w3);
                atomicAdd(&cs[2][rf], w2);
                atomicAdd(&cs[3][rf], w4);
            }
        }
    }
    __syncthreads();

    if (tid < 16) {
        int w = mt16 + tid;
        if (w < NN) {
            cb4[t * NN + w] = make_float4(cs[0][tid], cs[1][tid], cs[2][tid] + cs[3][tid], 0.0f);
            bb4[t * NN + w] = make_float4(br[t * NN + w], bra[t * NN + w],
                                          bd[t * NN + w] + bda[t * NN + w], 0.0f);
        }
    }

    // pack A-fragments: lane l=(g,r): elems 0..3 = W[r][ks*32+4g+e], 4..7 = +16 (0 if >=KP)
    for (int fr = tid; fr < 3 * KTILES * 64; fr += 256) {
        int mat = fr / (KTILES * 64);
        int rem = fr - mat * (KTILES * 64);
        int ks = rem >> 6, lq = rem & 63;
        int r = lq & 15, g = lq >> 4;
        const float* src = &rowbuf[mat][r][0];
        int k0 = ks * 32 + 4 * g;
        unsigned short h[8];
        #pragma unroll
        for (int e2 = 0; e2 < 4; ++e2) {
            h[e2] = f2h(src[k0 + e2]);                              // k0+e2 <= 207 always
            int kb = k0 + 16 + e2;
            h[4 + e2] = (kb < KP) ? f2h(src[kb]) : (unsigned short)0;
        }
        uint4 pv;
        pv.x = (unsigned)h[0] | ((unsigned)h[1] << 16);
        pv.y = (unsigned)h[2] | ((unsigned)h[3] << 16);
        pv.z = (unsigned)h[4] | ((unsigned)h[5] << 16);
        pv.w = (unsigned)h[6] | ((unsigned)h[7] << 16);
        size_t o = ((size_t)(t * MTILES + mt) * 3 + mat) * CH_U16 + (size_t)ks * 512 + (size_t)lq * 8;
        *(uint4*)(Wpack + o) = pv;
    }
}

// K2: MFMA main. Block (chunk, b): 512 thr = 8 waves, wave wv owns 16 cols.
// x staged row-major f16 [208][128] with swizzle stored_col = col ^ (((k>>2)&3)<<4).
// Every consumer read (frag build, epilogue xq) has (row>>2)&3 == g, so group g reads
// the disjoint dword window 8*(wv^g): conflict-free (<=2 lanes/dword).
// LDS 53,248 B -> 3 blocks/CU (24 waves); launch_bounds(512,4) -> 128-reg budget, no spills.
// B-frags register-resident; A streamed linearly from packed global (L1-hot across waves);
// epilogue xq from LDS f16, cb/bb tables direct (L1-hot).
__global__ __launch_bounds__(512, 4) void k_mfma(
    const float* __restrict__ inputs, const int* __restrict__ ind,
    const unsigned short* __restrict__ Wpack,
    const float4* __restrict__ cb4, const float4* __restrict__ bb4,
    float* __restrict__ out) {
    __shared__ unsigned short xs[KP * LCC];   // 53248 B
    const int b = blockIdx.y, chunk = blockIdx.x, tid = threadIdx.x;
    const int t = ind[b] / 12;

    // zero pad row 207 (read by frag build for ks=6,g=3,e=3; never output)
    if (tid < 64) ((unsigned*)(xs + 207 * LCC))[tid] = 0u;

    // stage x rows 0..206, swizzled
    const float* xb = inputs + (size_t)b * (2 * NN * LL) + (size_t)chunk * LCC;
    for (int i = tid; i < 207 * 32; i += 512) {
        int k  = i >> 5;
        int c4 = (i & 31) << 2;
        float4 v = *(const float4*)(xb + (size_t)k * LL + c4);
        int gk = (k >> 2) & 3;
        ushort4 h;
        h.x = f2h(v.x); h.y = f2h(v.y); h.z = f2h(v.z); h.w = f2h(v.w);
        *(ushort4*)&xs[k * LCC + (c4 ^ (gk << 4))] = h;
    }
    __syncthreads();

    const int l  = tid & 63, wv = tid >> 6;
    const int r  = l & 15,  g  = l >> 4;
    const int col  = wv * 16 + r;
    const int colx = col ^ (g << 4);           // swizzled: (k>>2)&3 == g for all our reads
    const _Float16* xh = (const _Float16*)xs;

    // B fragments: B[k][col]; elems 0..3 = k in [4g,4g+3], 4..7 = +16; tile 6 hi = 0
    half8 bf[KTILES];
    #pragma unroll
    for (int ks = 0; ks < KTILES - 1; ++ks) {
        half8 v;
        int k0 = ks * 32 + 4 * g;
        #pragma unroll
        for (int e = 0; e < 4; ++e) {
            v[e]     = xh[(k0 + e) * LCC + colx];
            v[4 + e] = xh[(k0 + 16 + e) * LCC + colx];
        }
        bf[ks] = v;
    }
    {
        half8 v = {0, 0, 0, 0, 0, 0, 0, 0};
        int k0 = 192 + 4 * g;
        #pragma unroll
        for (int e = 0; e < 4; ++e) v[e] = xh[(k0 + e) * LCC + colx];   // row 207 is zero
        bf[KTILES - 1] = v;
    }

    const unsigned short* Ap = Wpack + (size_t)t * T_U16 + (size_t)l * 8;
    const float4* cbp = cb4 + (size_t)t * NN;
    const float4* bbp = bb4 + (size_t)t * NN;
    float* ob = out + (size_t)b * ((size_t)NN * LL) + (size_t)chunk * LCC + col;

    for (int mt = 0; mt < MTILES; ++mt) {
        f32x4 aR = {0.f, 0.f, 0.f, 0.f};
        f32x4 aA = {0.f, 0.f, 0.f, 0.f};
        f32x4 aD = {0.f, 0.f, 0.f, 0.f};
        #pragma unroll
        for (int ks = 0; ks < KTILES; ++ks) {
            half8 a = __builtin_bit_cast(half8, *(const uint4*)(Ap + ks * 512));
            aR = __builtin_amdgcn_mfma_f32_16x16x32_f16(a, bf[ks], aR, 0, 0, 0);
        }
        #pragma unroll
        for (int ks = 0; ks < KTILES; ++ks) {
            half8 a = __builtin_bit_cast(half8, *(const uint4*)(Ap + CH_U16 + ks * 512));
            aA = __builtin_amdgcn_mfma_f32_16x16x32_f16(a, bf[ks], aA, 0, 0, 0);
        }
        #pragma unroll
        for (int ks = 0; ks < KTILES; ++ks) {
            half8 a = __builtin_bit_cast(half8, *(const uint4*)(Ap + 2 * CH_U16 + ks * 512));
            aD = __builtin_amdgcn_mfma_f32_16x16x32_f16(a, bf[ks], aD, 0, 0, 0);
        }
        Ap += 3 * CH_U16;

        const int rowb = mt * 16 + 4 * g;      // C/D row = 4g+q, col = lane&15
        #pragma unroll
        for (int q = 0; q < 4; ++q) {
            int row = rowb + q;
            if (row < NN) {
                float xq = (float)xh[row * LCC + colx];
                float4 cb = cbp[row], bb = bbp[row];
                float rr = aR[q] + cb.x * xq + bb.x;
                float ra = aA[q] + bb.y;
                if (b != 0) ra += cb.y * xq;   // colsum(RW[0]) == 0 analytically
                float dd = aD[q] + cb.z * xq + bb.z;
                ob[(size_t)row * LL] = tanhfast(rr) + tanhfast(ra) + dd + xq;
            }
        }
    }
}

extern "C" void kernel_launch(void* const* d_in, const int* in_sizes, int n_in,
                              void* d_out, int out_size, void* d_ws, size_t ws_size,
                              hipStream_t stream) {
    const float* inputs = (const float*)d_in[0];
    const int*   ind    = (const int*)d_in[1];
    const int*   efrom  = (const int*)d_in[2];
    const int*   eto    = (const int*)d_in[3];
    const float* wr     = (const float*)d_in[4];
    const float* wd     = (const float*)d_in[5];
    const float* wra    = (const float*)d_in[6];
    const float* wda    = (const float*)d_in[7];
    const float* br     = (const float*)d_in[8];
    const float* bd     = (const float*)d_in[9];
    const float* bra    = (const float*)d_in[10];
    const float* bda    = (const float*)d_in[11];
    float* out = (float*)d_out;

    char* ws = (char*)d_ws;
    float4*         cb4   = (float4*)(ws + 0);
    float4*         bb4   = (float4*)(ws + 79488);
    unsigned short* Wpack = (unsigned short*)(ws + 158976);

    const int B = in_sizes[1];   // 64

    k_build<<<dim3(NT * MTILES), dim3(256), 0, stream>>>(
        efrom, eto, wr, wd, wra, wda, br, bd, bra, bda, Wpack, cb4, bb4);
    k_mfma<<<dim3(LL / LCC, B), dim3(512), 0, stream>>>(
        inputs, ind, Wpack, cb4, bb4, out);
}